// Round 6
// baseline (1055.606 us; speedup 1.0000x reference)
//
#include <hip/hip_runtime.h>
#include <hip/hip_bf16.h>

namespace {

typedef _Float16 h16;
typedef _Float16 f16x8 __attribute__((ext_vector_type(8)));
typedef _Float16 f16x4 __attribute__((ext_vector_type(4)));
typedef float    f32x4 __attribute__((ext_vector_type(4)));

constexpr int T_SEQ = 512;
constexpr int B_SZ  = 1024;
constexpr int H_DIM = 128;
constexpr int ROWS  = 16;    // batch rows per block (MFMA N-tile)
constexpr int NT    = 256;   // 4 waves, 1/SIMD -> ~512-VGPR budget per thread
constexpr int TILES = 2;     // 16-gate MFMA tiles per wave (4 waves x 32 gates)

template <int INDIM> struct StageT;
template <> struct StageT<64>  { using type = f16x4; };
template <> struct StageT<128> { using type = f16x8; };

// Persistent MFMA GRU layer.
//  - 4 waves, each owns 32 gate cols (2 MFMA tiles): halves the per-step LDS
//    broadcast bandwidth vs 8 waves (B-frags are re-read per wave).
//  - ROWP = KTOT+4 -> row stride == 2 mod 32 dwords: all LDS patterns
//    (b128 frag reads, h writes, stage writes) hit min cycles/bank.
//  - hx double-buffered, ONE barrier/step; h_old in regs; 2-deep prefetch;
//    biases folded into MFMA C-init.
// Frag convention verified on HW (rounds 4/5, absmax 1.2e-4):
//  A row = lane&15 (gate within tile), k = (lane>>4)*8 + e + 32*ks
//  B col = lane&15 (batch), same k;  D: col = lane&15, row = (lane>>4)*4 + i
template <int INDIM, typename InT, bool STORE_ALL>
__global__ __launch_bounds__(NT, 1)
void gru_mfma(const InT* __restrict__ in,     // l0: x [B][T][64] f32; l1: h1 [T][B][128] f16
              const float* __restrict__ w_ih, // [384][INDIM]
              const float* __restrict__ w_hh, // [384][128]
              const float* __restrict__ b_ih, // [384]
              const float* __restrict__ b_hh, // [384]
              h16*  __restrict__ h1out,       // [T][B][128]   (STORE_ALL)
              float* __restrict__ h2out)      // [B][128]      (!STORE_ALL)
{
  constexpr int KSH  = H_DIM / 32;     // 4 K-steps over h
  constexpr int KSX  = INDIM / 32;     // 2 (l0) or 4 (l1) K-steps over input
  constexpr int KTOT = H_DIM + INDIM;
  constexpr int ROWP = KTOT + 4;       // stride: l0 196 h16 (98 dw), l1 260 (130 dw); ==2 mod 32

  using Stage = typename StageT<INDIM>::type;

  __shared__ __align__(16) h16 hx[2][ROWS][ROWP];  // [buf][batch][h(128) | in(INDIM) | pad]

  const int tid = threadIdx.x;
  const int wv  = tid >> 6;        // wave 0..3 -> 32-gate-col group
  const int ln  = tid & 63;
  const int q   = ln >> 4;         // k-chunk / D-row group
  const int lr  = ln & 15;         // A: gate row within tile; B/D: batch col
  const int r0  = blockIdx.x * ROWS;
  int j0t[TILES];
  #pragma unroll
  for (int ti = 0; ti < TILES; ++ti) j0t[ti] = wv * 32 + ti * 16 + q * 4;

  // ---- weights -> fp16 frags (arch VGPRs), once ----
  f16x8 wA[3][TILES][KSH];   // w_hh rows (recurrent GEMM A-operand)
  f16x8 wB[3][TILES][KSX];   // w_ih rows (input GEMM A-operand)
  #pragma unroll
  for (int p = 0; p < 3; ++p) {
    #pragma unroll
    for (int ti = 0; ti < TILES; ++ti) {
      const int g = p * H_DIM + wv * 32 + ti * 16 + lr;
      #pragma unroll
      for (int ks = 0; ks < KSH; ++ks) {
        const float* pw = w_hh + (size_t)g * H_DIM + ks * 32 + q * 8;
        const float4 v0 = *(const float4*)(pw);
        const float4 v1 = *(const float4*)(pw + 4);
        f16x8 f;
        f[0]=(h16)v0.x; f[1]=(h16)v0.y; f[2]=(h16)v0.z; f[3]=(h16)v0.w;
        f[4]=(h16)v1.x; f[5]=(h16)v1.y; f[6]=(h16)v1.z; f[7]=(h16)v1.w;
        wA[p][ti][ks] = f;
      }
      #pragma unroll
      for (int ks = 0; ks < KSX; ++ks) {
        const float* pw = w_ih + (size_t)g * INDIM + ks * 32 + q * 8;
        const float4 v0 = *(const float4*)(pw);
        const float4 v1 = *(const float4*)(pw + 4);
        f16x8 f;
        f[0]=(h16)v0.x; f[1]=(h16)v0.y; f[2]=(h16)v0.z; f[3]=(h16)v0.w;
        f[4]=(h16)v1.x; f[5]=(h16)v1.y; f[6]=(h16)v1.z; f[7]=(h16)v1.w;
        wB[p][ti][ks] = f;
      }
    }
  }

  // ---- bias C-init vectors for this lane's gate cols, per tile ----
  f32x4 bR[TILES], bZ[TILES], bNx[TILES], bNh[TILES];
  #pragma unroll
  for (int ti = 0; ti < TILES; ++ti) {
    const int j0 = j0t[ti];
    const float4 ir  = *(const float4*)&b_ih[j0];
    const float4 hr  = *(const float4*)&b_hh[j0];
    const float4 iz  = *(const float4*)&b_ih[H_DIM + j0];
    const float4 hz  = *(const float4*)&b_hh[H_DIM + j0];
    const float4 in_ = *(const float4*)&b_ih[2 * H_DIM + j0];
    const float4 hn  = *(const float4*)&b_hh[2 * H_DIM + j0];
    bR[ti][0]=ir.x+hr.x; bR[ti][1]=ir.y+hr.y; bR[ti][2]=ir.z+hr.z; bR[ti][3]=ir.w+hr.w;
    bZ[ti][0]=iz.x+hz.x; bZ[ti][1]=iz.y+hz.y; bZ[ti][2]=iz.z+hz.z; bZ[ti][3]=iz.w+hz.w;
    bNx[ti][0]=in_.x; bNx[ti][1]=in_.y; bNx[ti][2]=in_.z; bNx[ti][3]=in_.w;
    bNh[ti][0]=hn.x;  bNh[ti][1]=hn.y;  bNh[ti][2]=hn.z;  bNh[ti][3]=hn.w;
  }

  // ---- staging ids: 256 threads -> (batch row sr, chunk si) ----
  const int sr = tid >> 4;         // 0..15
  const int si = tid & 15;         // 0..15

  auto load_stage = [&](int t, Stage& dst) {
    if constexpr (INDIM == 64) {   // x [B][T][64] f32 -> convert inline, 16B/lane
      const float4 v = *(const float4*)(in + ((size_t)(r0 + sr) * T_SEQ + t) * 64 + si * 4);
      dst[0] = (h16)v.x; dst[1] = (h16)v.y; dst[2] = (h16)v.z; dst[3] = (h16)v.w;
    } else {                       // h1 [T][B][128] f16, 16B/lane
      dst = *(const Stage*)(in + ((size_t)t * B_SZ + (r0 + sr)) * 128 + si * 8);
    }
  };
  auto write_stage = [&](int buf, const Stage& s) {
    if constexpr (INDIM == 64) *(f16x4*)&hx[buf][sr][H_DIM + si * 4] = s;
    else                       *(f16x8*)&hx[buf][sr][H_DIM + si * 8] = s;
  };

  // ---- prologue: h(0)=0 and in(0) into buf 0; in(1) into regs ----
  {
    f16x8 z; z[0]=z[1]=z[2]=z[3]=z[4]=z[5]=z[6]=z[7] = (h16)0.f;
    *(f16x8*)&hx[0][tid >> 4][(tid & 15) * 8] = z;   // 16 x 128 h16 = 256 x f16x8
  }
  Stage s0; load_stage(0, s0); write_stage(0, s0);
  Stage sA; load_stage(1, sA);    // in(1), written during step 0
  Stage sB;                       // in(2), loaded during step 0
  f16x4 h_old[TILES];
  #pragma unroll
  for (int ti = 0; ti < TILES; ++ti) { h_old[ti][0]=h_old[ti][1]=h_old[ti][2]=h_old[ti][3]=(h16)0.f; }
  __syncthreads();

  auto step = [&](int t, int cur, Stage& s_use, Stage& s_load) {
    // B-frags from hx[cur] (conflict-free per the stride analysis)
    f16x8 bh[KSH], bx[KSX];
    #pragma unroll
    for (int ks = 0; ks < KSH; ++ks)
      bh[ks] = *(const f16x8*)&hx[cur][lr][ks * 32 + q * 8];
    #pragma unroll
    for (int ks = 0; ks < KSX; ++ks)
      bx[ks] = *(const f16x8*)&hx[cur][lr][H_DIM + ks * 32 + q * 8];

    // prefetch in(t+2) — 2-step window hides memory latency
    load_stage((t + 2 < T_SEQ) ? t + 2 : T_SEQ - 1, s_load);

    // MFMA: per tile 4 independent chains, biases pre-loaded as C-init
    f32x4 aR[TILES], aZ[TILES], aNh[TILES], aNx[TILES];
    #pragma unroll
    for (int ti = 0; ti < TILES; ++ti) { aR[ti]=bR[ti]; aZ[ti]=bZ[ti]; aNh[ti]=bNh[ti]; aNx[ti]=bNx[ti]; }
    #pragma unroll
    for (int ks = 0; ks < KSH; ++ks) {
      #pragma unroll
      for (int ti = 0; ti < TILES; ++ti) {
        aR[ti]  = __builtin_amdgcn_mfma_f32_16x16x32_f16(wA[0][ti][ks], bh[ks], aR[ti], 0, 0, 0);
        aZ[ti]  = __builtin_amdgcn_mfma_f32_16x16x32_f16(wA[1][ti][ks], bh[ks], aZ[ti], 0, 0, 0);
        aNh[ti] = __builtin_amdgcn_mfma_f32_16x16x32_f16(wA[2][ti][ks], bh[ks], aNh[ti], 0, 0, 0);
      }
    }
    #pragma unroll
    for (int ks = 0; ks < KSX; ++ks) {
      #pragma unroll
      for (int ti = 0; ti < TILES; ++ti) {
        aR[ti]  = __builtin_amdgcn_mfma_f32_16x16x32_f16(wB[0][ti][ks], bx[ks], aR[ti], 0, 0, 0);
        aZ[ti]  = __builtin_amdgcn_mfma_f32_16x16x32_f16(wB[1][ti][ks], bx[ks], aZ[ti], 0, 0, 0);
        aNx[ti] = __builtin_amdgcn_mfma_f32_16x16x32_f16(wB[2][ti][ks], bx[ks], aNx[ti], 0, 0, 0);
      }
    }

    // gates fully in-lane; h_old is this lane's own previous output
    #pragma unroll
    for (int ti = 0; ti < TILES; ++ti) {
      f16x4 nv4;
      float hnv[4];
      #pragma unroll
      for (int i = 0; i < 4; ++i) {
        const float rg = __builtin_amdgcn_rcpf(1.f + __expf(-aR[ti][i]));
        const float zg = __builtin_amdgcn_rcpf(1.f + __expf(-aZ[ti][i]));
        const float na = aNx[ti][i] + rg * aNh[ti][i];
        const float e2 = __expf(2.f * na);
        const float ng = 1.f - 2.f * __builtin_amdgcn_rcpf(e2 + 1.f);
        const float ho = (float)h_old[ti][i];
        const float hn = ng + zg * (ho - ng);
        hnv[i] = hn;
        nv4[i] = (h16)hn;
      }
      h_old[ti] = nv4;

      *(f16x4*)&hx[cur ^ 1][lr][j0t[ti]] = nv4;      // h(t+1) into other buffer
      if constexpr (STORE_ALL) {
        *(f16x4*)&h1out[((size_t)t * B_SZ + r0 + lr) * H_DIM + j0t[ti]] = nv4;
      } else {
        if (t == T_SEQ - 1)
          *(float4*)&h2out[(size_t)(r0 + lr) * H_DIM + j0t[ti]] =
              make_float4(hnv[0], hnv[1], hnv[2], hnv[3]);
      }
    }
    write_stage(cur ^ 1, s_use);
    __syncthreads();   // single barrier: buf[cur^1] complete
  };

  #pragma unroll 1
  for (int t = 0; t < T_SEQ; t += 2) {
    step(t,     0, sA, sB);   // reads buf0, writes buf1
    step(t + 1, 1, sB, sA);   // reads buf1, writes buf0
  }
}

// FC head: out = fc2( BN( relu( fc1(h2_last) ) ) ); one row per block.
__global__ __launch_bounds__(64)
void head_kernel(const float* __restrict__ h2,     // (B, H) f32
                 const float* __restrict__ fc1_w,  // (64, 128)
                 const float* __restrict__ fc1_b,  // (64)
                 const float* __restrict__ fc2_w,  // (2, 64)
                 const float* __restrict__ fc2_b,  // (2)
                 const float* __restrict__ gamma,
                 const float* __restrict__ beta,
                 const float* __restrict__ mean,
                 const float* __restrict__ var,
                 float* __restrict__ out)          // (B, 2)
{
  const int row = blockIdx.x;
  const int j   = threadIdx.x;   // 0..63
  __shared__ __align__(16) float hrow[H_DIM];
  __shared__ __align__(16) float act[64];

  hrow[j]      = h2[(size_t)row * H_DIM + j];
  hrow[64 + j] = h2[(size_t)row * H_DIM + 64 + j];
  __syncthreads();

  float s = fc1_b[j];
  const float4* wr = reinterpret_cast<const float4*>(fc1_w + (size_t)j * H_DIM);
  #pragma unroll
  for (int k4 = 0; k4 < H_DIM / 4; ++k4) {
    const float4 w = wr[k4];
    const float4 h = reinterpret_cast<const float4*>(hrow)[k4];
    s += w.x * h.x + w.y * h.y + w.z * h.z + w.w * h.w;
  }
  s = fmaxf(s, 0.f);
  s = (s - mean[j]) * rsqrtf(var[j] + 1e-5f) * gamma[j] + beta[j];
  act[j] = s;
  __syncthreads();

  if (j < 2) {
    float o = fc2_b[j];
    #pragma unroll
    for (int k = 0; k < 64; ++k) o += fc2_w[(size_t)j * 64 + k] * act[k];
    out[(size_t)row * 2 + j] = o;
  }
}

} // namespace

extern "C" void kernel_launch(void* const* d_in, const int* in_sizes, int n_in,
                              void* d_out, int out_size, void* d_ws, size_t ws_size,
                              hipStream_t stream) {
  const float* x     = (const float*)d_in[0];
  const float* w_ih0 = (const float*)d_in[1];
  const float* w_hh0 = (const float*)d_in[2];
  const float* b_ih0 = (const float*)d_in[3];
  const float* b_hh0 = (const float*)d_in[4];
  const float* w_ih1 = (const float*)d_in[5];
  const float* w_hh1 = (const float*)d_in[6];
  const float* b_ih1 = (const float*)d_in[7];
  const float* b_hh1 = (const float*)d_in[8];
  const float* fc1_w = (const float*)d_in[9];
  const float* fc1_b = (const float*)d_in[10];
  const float* fc2_w = (const float*)d_in[11];
  const float* fc2_b = (const float*)d_in[12];
  const float* gamma = (const float*)d_in[13];
  const float* beta  = (const float*)d_in[14];
  const float* mean  = (const float*)d_in[15];
  const float* var   = (const float*)d_in[16];
  float* out = (float*)d_out;

  char* ws = (char*)d_ws;
  const size_t h2_bytes = (size_t)B_SZ * H_DIM * sizeof(float);           // 512 KB
  const size_t h1_bytes = (size_t)T_SEQ * B_SZ * H_DIM * sizeof(h16);     // 134 MB
  if (ws_size < h2_bytes + h1_bytes) return;  // fail visibly

  float* h2 = (float*)ws;
  h16*   h1 = (h16*)(ws + h2_bytes);

  gru_mfma<64, float, true><<<dim3(B_SZ / ROWS), dim3(NT), 0, stream>>>(
      x, w_ih0, w_hh0, b_ih0, b_hh0, h1, nullptr);
  gru_mfma<128, h16, false><<<dim3(B_SZ / ROWS), dim3(NT), 0, stream>>>(
      h1, w_ih1, w_hh1, b_ih1, b_hh1, nullptr, h2);
  head_kernel<<<dim3(B_SZ), dim3(64), 0, stream>>>(
      h2, fc1_w, fc1_b, fc2_w, fc2_b, gamma, beta, mean, var, out);
}